// Round 1
// baseline (6536.365 us; speedup 1.0000x reference)
//
#include <hip/hip_runtime.h>
#include <hip/hip_bf16.h>

typedef short s16x8 __attribute__((ext_vector_type(8)));
typedef float f32x4 __attribute__((ext_vector_type(4)));

#define HEADS 24
#define HDIM  128
#define QBLK  54
#define ROWSTRIDE (HEADS * HDIM)   // 3072 floats per canvas position

// rope table offsets (floats) inside d_ws
#define TC 0
#define TS 96
#define YC 192
#define YS 1312
#define XC 2432
#define XS 4224

__device__ __forceinline__ short f2bf(float f) {
    union { float f; unsigned u; } x; x.f = f;
    unsigned u = (x.u + 0x7fffu + ((x.u >> 16) & 1u)) >> 16;
    return (short)u;
}

// cos/sin lookup for pair index p (0..63) at glued coords (tg, yg, xg)
__device__ __forceinline__ void rope_cs(const float* __restrict__ W, int tg, int yg, int xg,
                                        int p, float& c, float& s) {
    if (p < 8)       { c = W[TC + tg*8  + p];        s = W[TS + tg*8  + p]; }
    else if (p < 36) { int j = p - 8;  c = W[YC + yg*28 + j]; s = W[YS + yg*28 + j]; }
    else             { int j = p - 36; c = W[XC + xg*28 + j]; s = W[XS + xg*28 + j]; }
}

// Build separable RoPE tables on glued canvas. T: 12 pos x 8 pairs (pos=t).
// Y: 40 glued pos x 28 pairs (pos = gy-8). X: 64 glued pos x 28 pairs (pos = gx-8).
// theta=256=2^8: dim16 freq_j = 2^-j ; dim56 freq_j = 2^(-2j/7)
__global__ void rope_tables_k(float* __restrict__ W) {
    int i = blockIdx.x * blockDim.x + threadIdx.x;
    if (i < 96) {
        int t = i >> 3, j = i & 7;
        float ang = (float)t * exp2f(-(float)j);
        float s, c; sincosf(ang, &s, &c);
        W[TC + i] = c; W[TS + i] = s;
    } else if (i < 96 + 1120) {
        int e = i - 96; int gy = e / 28, j = e % 28;
        float ang = (float)(gy - 8) * exp2f(-2.0f * (float)j / 7.0f);
        float s, c; sincosf(ang, &s, &c);
        W[YC + e] = c; W[YS + e] = s;
    } else if (i < 96 + 1120 + 1792) {
        int e = i - 1216; int gx = e / 28, j = e % 28;
        float ang = (float)(gx - 8) * exp2f(-2.0f * (float)j / 7.0f);
        float s, c; sincosf(ang, &s, &c);
        W[XC + e] = c; W[XS + e] = s;
    }
}

// One workgroup = one (q-block, head). 512 threads = 8 waves; wave w owns q rows [32w, 32w+32).
__global__ __launch_bounds__(512, 2) void glued_attn_k(
    const float* __restrict__ Qg, const float* __restrict__ Kg, const float* __restrict__ Vg,
    const float* __restrict__ W, float* __restrict__ Og)
{
    __shared__ short Qs[256 * 128];   // 64 KB  rope'd Q, bf16, row-major
    __shared__ short Ks[64 * 128];    // 16 KB  rope'd K chunk, bf16, row-major
    __shared__ short Vt[128 * 72];    // 18 KB  V chunk, bf16, transposed [dim][kv], stride 72
    __shared__ short Ps[256 * 64];    // 32 KB  P (softmaxed scores), bf16

    const int tid  = threadIdx.x;
    const int wgid = blockIdx.x;
    const int h  = wgid / QBLK;
    const int qb = wgid % QBLK;
    const int bt = qb / 18, by = (qb % 18) / 6, bx = qb % 6;

    // ---- stage Q tile with RoPE, fold log2(e)/sqrt(128) into Q ----
    {
        const int r    = tid >> 1;
        const int half = tid & 1;
        const int it = r >> 6, iy = (r >> 3) & 7, ix = r & 7;
        const int t = bt*4 + it, y = by*8 + iy, x = bx*8 + ix;
        const int l = (t*24 + y)*48 + x;
        const float* src = Qg + (size_t)l * ROWSTRIDE + h * HDIM + half * 64;
        short* dst = &Qs[r * 128 + half * 64];
        const float qscale = 1.442695041f * 0.0883883476f;
#pragma unroll
        for (int j = 0; j < 16; ++j) {
            float4 f = ((const float4*)src)[j];
            int p0 = half * 32 + j * 2;
            float c0, s0, c1, s1;
            rope_cs(W, t, y + 8, x + 8, p0,     c0, s0);
            rope_cs(W, t, y + 8, x + 8, p0 + 1, c1, s1);
            dst[j*4+0] = f2bf((f.x*c0 - f.y*s0) * qscale);
            dst[j*4+1] = f2bf((f.y*c0 + f.x*s0) * qscale);
            dst[j*4+2] = f2bf((f.z*c1 - f.w*s1) * qscale);
            dst[j*4+3] = f2bf((f.w*c1 + f.z*s1) * qscale);
        }
    }
    __syncthreads();

    const int wv   = tid >> 6;        // wave 0..7
    const int lane = tid & 63;
    const int ln   = lane & 15;
    const int quad = lane >> 4;       // 0..3

    // Q A-frags resident: A[m=ln][k=quad*8+j], k-window ks*32
    s16x8 qf[2][4];
#pragma unroll
    for (int p = 0; p < 2; ++p) {
        const int row = (2*wv + p) * 16 + ln;
#pragma unroll
        for (int ks = 0; ks < 4; ++ks)
            qf[p][ks] = *(const s16x8*)&Qs[row * 128 + ks * 32 + quad * 8];
    }

    f32x4 o[2][8];
#pragma unroll
    for (int p = 0; p < 2; ++p)
#pragma unroll
        for (int dt = 0; dt < 8; ++dt)
            o[p][dt] = (f32x4){0.f, 0.f, 0.f, 0.f};
    float m_r[2][4], l_r[2][4];
#pragma unroll
    for (int p = 0; p < 2; ++p)
#pragma unroll
        for (int r = 0; r < 4; ++r) { m_r[p][r] = -1e30f; l_r[p][r] = 0.f; }

    // ---- kv loop: 27 blocks x 4 chunks of 64 rows ----
    for (int kb = 0; kb < 27; ++kb) {
        const int kbt = kb / 9;
        const int kby = by + (kb % 9) / 3;
        const int kbx = bx + (kb % 3);
        for (int ch = 0; ch < 4; ++ch) {
            __syncthreads();  // all waves done reading previous chunk
            {
                const int kr  = tid >> 3;   // 0..63
                const int seg = tid & 7;
                const int n  = ch * 64 + kr;
                const int it = n >> 6, iy = (n >> 3) & 7, ixx = n & 7;
                const int kt = kbt*4 + it, ky = kby*8 + iy, kx = kbx*8 + ixx;
                const int oy = (ky + 16) % 24, ox = (kx + 40) % 48;   // un-glue (wrap)
                const int lk = (kt*24 + oy)*48 + ox;
                const int d0 = seg * 16;
                const float* srcK = Kg + (size_t)lk * ROWSTRIDE + h * HDIM + d0;
                const float* srcV = Vg + (size_t)lk * ROWSTRIDE + h * HDIM + d0;
                short* dk = &Ks[kr * 128 + d0];
#pragma unroll
                for (int j = 0; j < 4; ++j) {
                    float4 f = ((const float4*)srcK)[j];
                    int p0 = (d0 >> 1) + j * 2;
                    float c0, s0, c1, s1;
                    rope_cs(W, kt, ky, kx, p0,     c0, s0);
                    rope_cs(W, kt, ky, kx, p0 + 1, c1, s1);
                    dk[j*4+0] = f2bf(f.x*c0 - f.y*s0);
                    dk[j*4+1] = f2bf(f.y*c0 + f.x*s0);
                    dk[j*4+2] = f2bf(f.z*c1 - f.w*s1);
                    dk[j*4+3] = f2bf(f.w*c1 + f.z*s1);
                }
#pragma unroll
                for (int j = 0; j < 4; ++j) {
                    float4 f = ((const float4*)srcV)[j];
                    Vt[(d0 + j*4 + 0) * 72 + kr] = f2bf(f.x);
                    Vt[(d0 + j*4 + 1) * 72 + kr] = f2bf(f.y);
                    Vt[(d0 + j*4 + 2) * 72 + kr] = f2bf(f.z);
                    Vt[(d0 + j*4 + 3) * 72 + kr] = f2bf(f.w);
                }
            }
            __syncthreads();

            // ---- S = Q K^T (16x16 tiles), online softmax, P -> LDS ----
#pragma unroll
            for (int p = 0; p < 2; ++p) {
                f32x4 sa[4];
#pragma unroll
                for (int ct = 0; ct < 4; ++ct) sa[ct] = (f32x4){0.f, 0.f, 0.f, 0.f};
#pragma unroll
                for (int ct = 0; ct < 4; ++ct)
#pragma unroll
                    for (int ks = 0; ks < 4; ++ks) {
                        s16x8 bf = *(const s16x8*)&Ks[(ct*16 + ln) * 128 + ks*32 + quad*8];
                        sa[ct] = __builtin_amdgcn_mfma_f32_16x16x32_bf16(qf[p][ks], bf, sa[ct], 0, 0, 0);
                    }
                // rows held: quad*4 + r ; cols: ct*16 + ln
                float cm[4];
#pragma unroll
                for (int r = 0; r < 4; ++r)
                    cm[r] = fmaxf(fmaxf(sa[0][r], sa[1][r]), fmaxf(sa[2][r], sa[3][r]));
#pragma unroll
                for (int r = 0; r < 4; ++r) {
                    cm[r] = fmaxf(cm[r], __shfl_xor(cm[r], 1));
                    cm[r] = fmaxf(cm[r], __shfl_xor(cm[r], 2));
                    cm[r] = fmaxf(cm[r], __shfl_xor(cm[r], 4));
                    cm[r] = fmaxf(cm[r], __shfl_xor(cm[r], 8));
                }
                float mn[4], al[4], rs[4];
#pragma unroll
                for (int r = 0; r < 4; ++r) {
                    mn[r] = fmaxf(m_r[p][r], cm[r]);
                    al[r] = exp2f(m_r[p][r] - mn[r]);
                    m_r[p][r] = mn[r];
                    rs[r] = 0.f;
                }
#pragma unroll
                for (int ct = 0; ct < 4; ++ct)
#pragma unroll
                    for (int r = 0; r < 4; ++r) {
                        float pv = exp2f(sa[ct][r] - mn[r]);
                        sa[ct][r] = pv;
                        rs[r] += pv;
                    }
#pragma unroll
                for (int r = 0; r < 4; ++r) {
                    rs[r] += __shfl_xor(rs[r], 1);
                    rs[r] += __shfl_xor(rs[r], 2);
                    rs[r] += __shfl_xor(rs[r], 4);
                    rs[r] += __shfl_xor(rs[r], 8);
                    l_r[p][r] = l_r[p][r] * al[r] + rs[r];
                }
                const int rowb = (2*wv + p) * 16 + quad * 4;
#pragma unroll
                for (int ct = 0; ct < 4; ++ct)
#pragma unroll
                    for (int r = 0; r < 4; ++r)
                        Ps[(rowb + r) * 64 + ct*16 + ln] = f2bf(sa[ct][r]);
#pragma unroll
                for (int dt = 0; dt < 8; ++dt)
#pragma unroll
                    for (int r = 0; r < 4; ++r)
                        o[p][dt][r] *= al[r];
            }

            // ---- O += P V  (P from LDS in A-layout; Vt gives B-layout contiguous) ----
#pragma unroll
            for (int p = 0; p < 2; ++p) {
                const int arow = (2*wv + p) * 16 + ln;
#pragma unroll
                for (int ks2 = 0; ks2 < 2; ++ks2) {
                    s16x8 af = *(const s16x8*)&Ps[arow * 64 + ks2*32 + quad*8];
#pragma unroll
                    for (int dt = 0; dt < 8; ++dt) {
                        s16x8 bf = *(const s16x8*)&Vt[(dt*16 + ln) * 72 + ks2*32 + quad*8];
                        o[p][dt] = __builtin_amdgcn_mfma_f32_16x16x32_bf16(af, bf, o[p][dt], 0, 0, 0);
                    }
                }
            }
        }
    }

    // ---- epilogue: normalize and store fp32 ----
#pragma unroll
    for (int p = 0; p < 2; ++p) {
#pragma unroll
        for (int r = 0; r < 4; ++r) {
            const float inv = 1.0f / l_r[p][r];
            const int rowl = (2*wv + p) * 16 + quad * 4 + r;
            const int it = rowl >> 6, iy = (rowl >> 3) & 7, ix = rowl & 7;
            const int l = ((bt*4 + it)*24 + by*8 + iy)*48 + bx*8 + ix;
            float* dst = Og + (size_t)l * ROWSTRIDE + h * HDIM;
#pragma unroll
            for (int dt = 0; dt < 8; ++dt)
                dst[dt*16 + ln] = o[p][dt][r] * inv;
        }
    }
}

extern "C" void kernel_launch(void* const* d_in, const int* in_sizes, int n_in,
                              void* d_out, int out_size, void* d_ws, size_t ws_size,
                              hipStream_t stream) {
    const float* q = (const float*)d_in[0];
    const float* k = (const float*)d_in[1];
    const float* v = (const float*)d_in[2];
    float* out = (float*)d_out;
    float* W = (float*)d_ws;   // 6016 floats of rope tables

    hipLaunchKernelGGL(rope_tables_k, dim3(12), dim3(256), 0, stream, W);
    hipLaunchKernelGGL(glued_attn_k, dim3(1296), dim3(512), 0, stream, q, k, v, W, out);
}